// Round 2
// baseline (141.049 us; speedup 1.0000x reference)
//
#include <hip/hip_runtime.h>

#define NUM_POSES 200

// ---- bf16 <-> f32 helpers (raw bits; RNE rounding on pack) ----
__device__ __forceinline__ float bf2f(unsigned int u16) {
    union { unsigned int u; float f; } v; v.u = u16 << 16; return v.f;
}
__device__ __forceinline__ unsigned int f2bf(float f) {
    union { float f; unsigned int u; } v; v.f = f;
    unsigned int r = v.u + 0x7FFFu + ((v.u >> 16) & 1u);
    return r >> 16;
}

// ---- Kernel 0: detect input dtypes from data, write flags to ws ----
// flags[0] = 1 if E is float32 (else bf16); flags[1] = 1 if n is int32 (else int64)
__global__ void detect_kernel(const unsigned short* __restrict__ E16,
                              const unsigned int* __restrict__ n32,
                              int* __restrict__ flags) {
    __shared__ unsigned int sany;
    int t = threadIdx.x;
    if (t == 0) sany = 0u;
    __syncthreads();
    unsigned int local = 0u;
    // E probe: true-bf16 N(0,1) values are all |v| < ~10; f32 mantissa halves
    // read as bf16 give random exponents -> huge/NaN with ~42% probability each.
    for (int k = t; k < 4096; k += 256) {
        float a = fabsf(bf2f(E16[k]));
        if (!(a <= 1e6f)) local |= 1u;   // NaN-safe: NaN fails (a<=1e6)
    }
    // n probe: int64 values in [0,200) have zero high words at odd int32 slots.
    if (t < 256 && n32[2 * t + 1] != 0u) local |= 2u;
    if (local) atomicOr(&sany, local);
    __syncthreads();
    if (t == 0) {
        flags[0] = (sany & 1u) ? 1 : 0;
        flags[1] = (sany & 2u) ? 1 : 0;
    }
}

// ---- Kernel 1: build 200 pose matrices (Rodrigues) into ws as fp32 ----
__global__ void pose_kernel(const void* __restrict__ Rv,
                            const void* __restrict__ Tv,
                            const int* __restrict__ flags,
                            float* __restrict__ M) {
    int p = threadIdx.x;
    if (p >= NUM_POSES) return;
    float wx, wy, wz, tx, ty, tz;
    if (flags[0]) {
        const float* R = (const float*)Rv; const float* T = (const float*)Tv;
        wx = R[3*p+0]; wy = R[3*p+1]; wz = R[3*p+2];
        tx = T[3*p+0]; ty = T[3*p+1]; tz = T[3*p+2];
    } else {
        const unsigned short* R = (const unsigned short*)Rv;
        const unsigned short* T = (const unsigned short*)Tv;
        wx = bf2f(R[3*p+0]); wy = bf2f(R[3*p+1]); wz = bf2f(R[3*p+2]);
        tx = bf2f(T[3*p+0]); ty = bf2f(T[3*p+1]); tz = bf2f(T[3*p+2]);
    }
    float t2 = wx*wx + wy*wy + wz*wz;
    float th = sqrtf(t2 + 1e-12f);
    float a  = sinf(th) / th;
    float b  = (1.0f - cosf(th)) / fmaxf(t2, 1e-12f);

    float* m = M + p * 16;
    m[0]  = 1.0f - b * (wy*wy + wz*wz);
    m[1]  = -a * wz + b * wx * wy;
    m[2]  =  a * wy + b * wx * wz;
    m[3]  = tx;
    m[4]  =  a * wz + b * wx * wy;
    m[5]  = 1.0f - b * (wx*wx + wz*wz);
    m[6]  = -a * wx + b * wy * wz;
    m[7]  = ty;
    m[8]  = -a * wy + b * wx * wz;
    m[9]  =  a * wx + b * wy * wz;
    m[10] = 1.0f - b * (wx*wx + wy*wy);
    m[11] = tz;
    m[12] = 0.0f; m[13] = 0.0f; m[14] = 0.0f; m[15] = 1.0f;
}

// ---- Kernel 2: out[i] = M(n[i]) @ E[i], dtype-adaptive ----
__global__ __launch_bounds__(256) void apply_kernel(
        const void* __restrict__ nin,
        const void* __restrict__ Ein,
        const float4* __restrict__ M,
        void* __restrict__ outv,
        const int* __restrict__ flags,
        int N) {
    int i = blockIdx.x * blockDim.x + threadIdx.x;
    if (i >= N) return;
    const int e_is_f32 = flags[0];
    const int n_is_i32 = flags[1];

    long long p = n_is_i32 ? (long long)((const int*)nin)[i]
                           : ((const long long*)nin)[i];
    float4 m0 = M[p * 4 + 0];
    float4 m1 = M[p * 4 + 1];
    float4 m2 = M[p * 4 + 2];
    // M row 3 = [0,0,0,1] -> output row 3 is E row 3 (passthrough)

    if (e_is_f32) {
        const float4* Ef = (const float4*)Ein + 4 * (size_t)i;
        float4 e0 = Ef[0], e1 = Ef[1], e2 = Ef[2], e3 = Ef[3];
        float4 r0, r1, r2;
        r0.x = m0.x*e0.x + m0.y*e1.x + m0.z*e2.x + m0.w*e3.x;
        r0.y = m0.x*e0.y + m0.y*e1.y + m0.z*e2.y + m0.w*e3.y;
        r0.z = m0.x*e0.z + m0.y*e1.z + m0.z*e2.z + m0.w*e3.z;
        r0.w = m0.x*e0.w + m0.y*e1.w + m0.z*e2.w + m0.w*e3.w;
        r1.x = m1.x*e0.x + m1.y*e1.x + m1.z*e2.x + m1.w*e3.x;
        r1.y = m1.x*e0.y + m1.y*e1.y + m1.z*e2.y + m1.w*e3.y;
        r1.z = m1.x*e0.z + m1.y*e1.z + m1.z*e2.z + m1.w*e3.z;
        r1.w = m1.x*e0.w + m1.y*e1.w + m1.z*e2.w + m1.w*e3.w;
        r2.x = m2.x*e0.x + m2.y*e1.x + m2.z*e2.x + m2.w*e3.x;
        r2.y = m2.x*e0.y + m2.y*e1.y + m2.z*e2.y + m2.w*e3.y;
        r2.z = m2.x*e0.z + m2.y*e1.z + m2.z*e2.z + m2.w*e3.z;
        r2.w = m2.x*e0.w + m2.y*e1.w + m2.z*e2.w + m2.w*e3.w;
        float4* Of = (float4*)outv + 4 * (size_t)i;
        Of[0] = r0; Of[1] = r1; Of[2] = r2; Of[3] = e3;
    } else {
        const uint4* Eb = (const uint4*)Ein + 2 * (size_t)i;
        uint4 e0 = Eb[0];   // rows 0,1
        uint4 e1 = Eb[1];   // rows 2,3
        float E00 = bf2f(e0.x & 0xFFFFu), E01 = bf2f(e0.x >> 16);
        float E02 = bf2f(e0.y & 0xFFFFu), E03 = bf2f(e0.y >> 16);
        float E10 = bf2f(e0.z & 0xFFFFu), E11 = bf2f(e0.z >> 16);
        float E12 = bf2f(e0.w & 0xFFFFu), E13 = bf2f(e0.w >> 16);
        float E20 = bf2f(e1.x & 0xFFFFu), E21 = bf2f(e1.x >> 16);
        float E22 = bf2f(e1.y & 0xFFFFu), E23 = bf2f(e1.y >> 16);
        float E30 = bf2f(e1.z & 0xFFFFu), E31 = bf2f(e1.z >> 16);
        float E32 = bf2f(e1.w & 0xFFFFu), E33 = bf2f(e1.w >> 16);

        float o00 = m0.x*E00 + m0.y*E10 + m0.z*E20 + m0.w*E30;
        float o01 = m0.x*E01 + m0.y*E11 + m0.z*E21 + m0.w*E31;
        float o02 = m0.x*E02 + m0.y*E12 + m0.z*E22 + m0.w*E32;
        float o03 = m0.x*E03 + m0.y*E13 + m0.z*E23 + m0.w*E33;
        float o10 = m1.x*E00 + m1.y*E10 + m1.z*E20 + m1.w*E30;
        float o11 = m1.x*E01 + m1.y*E11 + m1.z*E21 + m1.w*E31;
        float o12 = m1.x*E02 + m1.y*E12 + m1.z*E22 + m1.w*E32;
        float o13 = m1.x*E03 + m1.y*E13 + m1.z*E23 + m1.w*E33;
        float o20 = m2.x*E00 + m2.y*E10 + m2.z*E20 + m2.w*E30;
        float o21 = m2.x*E01 + m2.y*E11 + m2.z*E21 + m2.w*E31;
        float o22 = m2.x*E02 + m2.y*E12 + m2.z*E22 + m2.w*E32;
        float o23 = m2.x*E03 + m2.y*E13 + m2.z*E23 + m2.w*E33;

        uint4 r0, r1;
        r0.x = f2bf(o00) | (f2bf(o01) << 16);
        r0.y = f2bf(o02) | (f2bf(o03) << 16);
        r0.z = f2bf(o10) | (f2bf(o11) << 16);
        r0.w = f2bf(o12) | (f2bf(o13) << 16);
        r1.x = f2bf(o20) | (f2bf(o21) << 16);
        r1.y = f2bf(o22) | (f2bf(o23) << 16);
        r1.z = e1.z;   // bottom row passthrough
        r1.w = e1.w;
        uint4* Ob = (uint4*)outv + 2 * (size_t)i;
        Ob[0] = r0; Ob[1] = r1;
    }
}

extern "C" void kernel_launch(void* const* d_in, const int* in_sizes, int n_in,
                              void* d_out, int out_size, void* d_ws, size_t ws_size,
                              hipStream_t stream) {
    const void* n = d_in[0];
    const void* E = d_in[1];
    const void* R = d_in[2];
    const void* T = d_in[3];
    int*    flags = (int*)d_ws;                    // 2 ints
    float*      M = (float*)((char*)d_ws + 256);   // 200*16 fp32, 16B-aligned
    const int   N = in_sizes[0];

    detect_kernel<<<1, 256, 0, stream>>>((const unsigned short*)E,
                                         (const unsigned int*)n, flags);
    pose_kernel<<<1, 256, 0, stream>>>(R, T, flags, M);
    apply_kernel<<<(N + 255) / 256, 256, 0, stream>>>(
        n, E, (const float4*)M, d_out, flags, N);
}

// Round 3
// 134.418 us; speedup vs baseline: 1.0493x; 1.0493x over previous
//
#include <hip/hip_runtime.h>

#define NUM_POSES 200

// ---- bf16 <-> f32 helpers (raw bits; RNE rounding on pack) ----
__device__ __forceinline__ float bf2f(unsigned int u16) {
    union { unsigned int u; float f; } v; v.u = u16 << 16; return v.f;
}
__device__ __forceinline__ unsigned int f2bf(float f) {
    union { float f; unsigned int u; } v; v.f = f;
    unsigned int r = v.u + 0x7FFFu + ((v.u >> 16) & 1u);
    return r >> 16;
}

__device__ __forceinline__ float4 shfl4(float4 v, int src) {
    float4 r;
    r.x = __shfl(v.x, src);
    r.y = __shfl(v.y, src);
    r.z = __shfl(v.z, src);
    r.w = __shfl(v.w, src);
    return r;
}

// ---- Kernel 1: detect dtypes AND build the 200 pose matrices ----
// flags[0] = 1 if E is float32 (else bf16); flags[1] = 1 if n is int32 (else int64)
__global__ void prep_kernel(const unsigned short* __restrict__ E16,
                            const unsigned int* __restrict__ n32,
                            const void* __restrict__ Rv,
                            const void* __restrict__ Tv,
                            int* __restrict__ flags,
                            float* __restrict__ M) {
    __shared__ unsigned int sany;
    int t = threadIdx.x;
    if (t == 0) sany = 0u;
    __syncthreads();
    unsigned int local = 0u;
    // E probe: true-bf16 N(0,1) values all have |v| < ~10; f32 mantissa halves
    // read as bf16 give random exponents -> huge/NaN with high probability.
    for (int k = t; k < 4096; k += 256) {
        float a = fabsf(bf2f(E16[k]));
        if (!(a <= 1e6f)) local |= 1u;   // NaN also trips (NaN fails a<=1e6)
    }
    // n probe: int64 values in [0,200) have zero high words at odd int32 slots.
    if (n32[2 * t + 1] != 0u) local |= 2u;
    if (local) atomicOr(&sany, local);
    __syncthreads();
    unsigned int s = sany;
    if (t == 0) {
        flags[0] = (s & 1u) ? 1 : 0;
        flags[1] = (s & 2u) ? 1 : 0;
    }
    if (t >= NUM_POSES) return;
    int p = t;
    float wx, wy, wz, tx, ty, tz;
    if (s & 1u) {
        const float* R = (const float*)Rv; const float* T = (const float*)Tv;
        wx = R[3*p+0]; wy = R[3*p+1]; wz = R[3*p+2];
        tx = T[3*p+0]; ty = T[3*p+1]; tz = T[3*p+2];
    } else {
        const unsigned short* R = (const unsigned short*)Rv;
        const unsigned short* T = (const unsigned short*)Tv;
        wx = bf2f(R[3*p+0]); wy = bf2f(R[3*p+1]); wz = bf2f(R[3*p+2]);
        tx = bf2f(T[3*p+0]); ty = bf2f(T[3*p+1]); tz = bf2f(T[3*p+2]);
    }
    float t2 = wx*wx + wy*wy + wz*wz;
    float th = sqrtf(t2 + 1e-12f);
    float a  = sinf(th) / th;
    float b  = (1.0f - cosf(th)) / fmaxf(t2, 1e-12f);

    float* m = M + p * 16;
    m[0]  = 1.0f - b * (wy*wy + wz*wz);
    m[1]  = -a * wz + b * wx * wy;
    m[2]  =  a * wy + b * wx * wz;
    m[3]  = tx;
    m[4]  =  a * wz + b * wx * wy;
    m[5]  = 1.0f - b * (wx*wx + wz*wz);
    m[6]  = -a * wx + b * wy * wz;
    m[7]  = ty;
    m[8]  = -a * wy + b * wx * wz;
    m[9]  =  a * wx + b * wy * wz;
    m[10] = 1.0f - b * (wx*wx + wy*wy);
    m[11] = tz;
    m[12] = 0.0f; m[13] = 0.0f; m[14] = 0.0f; m[15] = 1.0f;
    // M row 3 = [0,0,0,1] lets apply_kernel treat ALL output rows uniformly:
    // out row 3 = 0*E0+0*E1+0*E2+1*E3 = E3 exactly (fp32, finite inputs).
}

// ---- Kernel 2: one OUTPUT ROW per thread (4 threads/element) ----
// Lane t loads float4 #t of E -> 16 B/lane, lane-consecutive, fully coalesced.
// The 3 sibling rows arrive via intra-wave shuffles (4-lane groups).
__global__ __launch_bounds__(256) void apply_kernel(
        const void* __restrict__ nin,
        const void* __restrict__ Ein,
        const float4* __restrict__ M,
        void* __restrict__ outv,
        const int* __restrict__ flags,
        int N) {
    int t = blockIdx.x * blockDim.x + threadIdx.x;   // row index
    int e = t >> 2;                                  // element
    int r = t & 3;                                   // row within element
    if (e >= N) return;
    const int e_is_f32 = flags[0];
    const int n_is_i32 = flags[1];

    long long p = n_is_i32 ? (long long)((const int*)nin)[e]
                           : ((const long long*)nin)[e];
    float4 m = M[p * 4 + r];          // 12.8 KB table: L1-resident
    int lb = (threadIdx.x & 63) & ~3; // lane of row 0 in my 4-lane group

    if (e_is_f32) {
        float4 myrow = ((const float4*)Ein)[t];
        float4 E0 = shfl4(myrow, lb + 0);
        float4 E1 = shfl4(myrow, lb + 1);
        float4 E2 = shfl4(myrow, lb + 2);
        float4 E3 = shfl4(myrow, lb + 3);
        float4 o;
        o.x = m.x*E0.x + m.y*E1.x + m.z*E2.x + m.w*E3.x;
        o.y = m.x*E0.y + m.y*E1.y + m.z*E2.y + m.w*E3.y;
        o.z = m.x*E0.z + m.y*E1.z + m.z*E2.z + m.w*E3.z;
        o.w = m.x*E0.w + m.y*E1.w + m.z*E2.w + m.w*E3.w;
        ((float4*)outv)[t] = o;
    } else {
        uint2 raw = ((const uint2*)Ein)[t];   // 4 bf16 = my row
        float4 myrow;
        myrow.x = bf2f(raw.x & 0xFFFFu); myrow.y = bf2f(raw.x >> 16);
        myrow.z = bf2f(raw.y & 0xFFFFu); myrow.w = bf2f(raw.y >> 16);
        float4 E0 = shfl4(myrow, lb + 0);
        float4 E1 = shfl4(myrow, lb + 1);
        float4 E2 = shfl4(myrow, lb + 2);
        float4 E3 = shfl4(myrow, lb + 3);
        float4 o;
        o.x = m.x*E0.x + m.y*E1.x + m.z*E2.x + m.w*E3.x;
        o.y = m.x*E0.y + m.y*E1.y + m.z*E2.y + m.w*E3.y;
        o.z = m.x*E0.z + m.y*E1.z + m.z*E2.z + m.w*E3.z;
        o.w = m.x*E0.w + m.y*E1.w + m.z*E2.w + m.w*E3.w;
        uint2 pk;
        pk.x = f2bf(o.x) | (f2bf(o.y) << 16);
        pk.y = f2bf(o.z) | (f2bf(o.w) << 16);
        ((uint2*)outv)[t] = pk;
    }
}

extern "C" void kernel_launch(void* const* d_in, const int* in_sizes, int n_in,
                              void* d_out, int out_size, void* d_ws, size_t ws_size,
                              hipStream_t stream) {
    const void* n = d_in[0];
    const void* E = d_in[1];
    const void* R = d_in[2];
    const void* T = d_in[3];
    int*    flags = (int*)d_ws;                    // 2 ints
    float*      M = (float*)((char*)d_ws + 256);   // 200*16 fp32, 16B-aligned
    const int   N = in_sizes[0];

    prep_kernel<<<1, 256, 0, stream>>>((const unsigned short*)E,
                                       (const unsigned int*)n, R, T, flags, M);
    const int rows = N * 4;
    apply_kernel<<<(rows + 255) / 256, 256, 0, stream>>>(
        n, E, (const float4*)M, d_out, flags, N);
}